// Round 18
// baseline (20.283 us; speedup 1.0000x reference)
//
#include <hip/hip_runtime.h>
#include <math.h>

#define BATCH   512
#define IN_DIM  256
#define OUT_DIM 256

// R18: NB=32 fused single-dispatch in PURE C (no inline asm). R16/R17's NaN
// is attributed to the op_sel inline-asm x 32-unroll x regalloc interaction
// (static audit of indices/numerics clean; arithmetic identical to passing
// R15). R12 proved v_pk_fma_f32 has no throughput edge on CDNA4 (2-pass
// execution == scalar fma rate), so scalar Horner loses nothing and removes
// the entire asm risk class. Redundancy: weight re-reads & coef exps halved
// vs R15 (BATCH/NB = 16 blocks share each (i,o) coefficient).
#define OT     8     // o per block
#define NSEG   32    // i-segments per block (tid>>3)
#define ISEG   8     // i's per segment
#define NB     32    // b per block (register accumulators)

#define PRESCALE 12.476649250079015f   // 18 * ln2

// Grid = (OUT_DIM/OT = 32, BATCH/NB = 16) = 512 blocks. One dispatch.
__launch_bounds__(256, 4)
__global__ void tropical_fused(const float* __restrict__ x,
                               const float* __restrict__ wp,
                               const float* __restrict__ wq,
                               float* __restrict__ out) {
    // Phase A: t[b][i], 32 b x 256 i (8192 f). Phase B: slab reduce
    // (32 slabs, stride NB*OT+1 = 257 -> 8224 f). Shared allocation.
    __shared__ float lds[NSEG * (NB * OT + 1)];   // 8224 floats = 32.9 KiB

    const int tid = threadIdx.x;
    const int o_l = tid & (OT - 1);
    const int b0  = blockIdx.y * NB;

    // ---- stage t = exp(x): 32 b-rows x 256 i (32 floats / thread) ----
    {
        const int r0 = tid >> 4;           // 0..15
        const int c  = (tid & 15) * 16;    // 0..240
#pragma unroll
        for (int p = 0; p < 2; ++p) {
            const int r = p * 16 + r0;
            const float* xr = x + (size_t)(b0 + r) * IN_DIM + c;
#pragma unroll
            for (int q = 0; q < 4; ++q) {
                const float4 v = *(const float4*)(xr + q * 4);
                float4 w;
                w.x = __expf(v.x); w.y = __expf(v.y);
                w.z = __expf(v.z); w.w = __expf(v.w);
                *(float4*)&lds[r * IN_DIM + c + q * 4] = w;
            }
        }
    }
    __syncthreads();

    float acc[NB];
#pragma unroll
    for (int b = 0; b < NB; ++b) acc[b] = 0.f;

    const int seg    = tid >> 3;           // 0..31
    const int i_base = seg * ISEG;
    const int o      = blockIdx.x * OT + o_l;
    const float* __restrict__ tb = lds + i_base;

#pragma unroll
    for (int g = 0; g < 2; ++g) {          // 2 groups of 4 i's
        // ---- in-register coefficient build: exp(w - 18ln2), plain C ----
        float cp[4][6], cq[4][6];
#pragma unroll
        for (int ii = 0; ii < 4; ++ii) {
            const int j = (i_base + g * 4 + ii) * OUT_DIM + o;
            const float2* P2 = (const float2*)wp + (size_t)j * 3;
            const float2* Q2 = (const float2*)wq + (size_t)j * 3;
            const float2 p0 = P2[0], p1 = P2[1], p2 = P2[2];
            const float2 q0 = Q2[0], q1 = Q2[1], q2 = Q2[2];
            cp[ii][0] = __expf(p0.x - PRESCALE);
            cp[ii][1] = __expf(p0.y - PRESCALE);
            cp[ii][2] = __expf(p1.x - PRESCALE);
            cp[ii][3] = __expf(p1.y - PRESCALE);
            cp[ii][4] = __expf(p2.x - PRESCALE);
            cp[ii][5] = __expf(p2.y - PRESCALE);
            cq[ii][0] = __expf(q0.x - PRESCALE);
            cq[ii][1] = __expf(q0.y - PRESCALE);
            cq[ii][2] = __expf(q1.x - PRESCALE);
            cq[ii][3] = __expf(q1.y - PRESCALE);
            cq[ii][4] = __expf(q2.x - PRESCALE);
            cq[ii][5] = __expf(q2.y - PRESCALE);
        }

        // ---- inner loop: scalar Horner x (P,Q) x 4 i's, 1 log2 pair ----
#pragma unroll
        for (int b = 0; b < NB; ++b) {
            const float4 tv = *(const float4*)(tb + b * IN_DIM + g * 4);
            const float t0 = tv.x, t1 = tv.y, t2 = tv.z, t3 = tv.w;

            float P0 = fmaf(fmaf(fmaf(fmaf(fmaf(cp[0][5], t0, cp[0][4]),
                         t0, cp[0][3]), t0, cp[0][2]), t0, cp[0][1]), t0, cp[0][0]);
            float P1 = fmaf(fmaf(fmaf(fmaf(fmaf(cp[1][5], t1, cp[1][4]),
                         t1, cp[1][3]), t1, cp[1][2]), t1, cp[1][1]), t1, cp[1][0]);
            float P2v = fmaf(fmaf(fmaf(fmaf(fmaf(cp[2][5], t2, cp[2][4]),
                         t2, cp[2][3]), t2, cp[2][2]), t2, cp[2][1]), t2, cp[2][0]);
            float P3 = fmaf(fmaf(fmaf(fmaf(fmaf(cp[3][5], t3, cp[3][4]),
                         t3, cp[3][3]), t3, cp[3][2]), t3, cp[3][1]), t3, cp[3][0]);

            float Q0 = fmaf(fmaf(fmaf(fmaf(fmaf(cq[0][5], t0, cq[0][4]),
                         t0, cq[0][3]), t0, cq[0][2]), t0, cq[0][1]), t0, cq[0][0]);
            float Q1 = fmaf(fmaf(fmaf(fmaf(fmaf(cq[1][5], t1, cq[1][4]),
                         t1, cq[1][3]), t1, cq[1][2]), t1, cq[1][1]), t1, cq[1][0]);
            float Q2v = fmaf(fmaf(fmaf(fmaf(fmaf(cq[2][5], t2, cq[2][4]),
                         t2, cq[2][3]), t2, cq[2][2]), t2, cq[2][1]), t2, cq[2][0]);
            float Q3 = fmaf(fmaf(fmaf(fmaf(fmaf(cq[3][5], t3, cq[3][4]),
                         t3, cq[3][3]), t3, cq[3][2]), t3, cq[3][1]), t3, cq[3][0]);

            const float mp = (P0 * P1) * (P2v * P3);   // in [7e-23, 1.6e21]
            const float mq = (Q0 * Q1) * (Q2v * Q3);
            acc[b] += __log2f(mp) - __log2f(mq);
        }
    }

    __syncthreads();   // done with t; reuse LDS as reduce buffer
#pragma unroll
    for (int b = 0; b < NB; ++b)
        lds[seg * (NB * OT + 1) + b * OT + o_l] = acc[b];
    __syncthreads();

    // 256 outputs = 256 threads: each sums its (br, orr) across 32 slabs.
    {
        const int br  = tid >> 3;          // 0..31
        const int orr = tid & (OT - 1);    // 0..7
        float s = 0.f;
#pragma unroll
        for (int g2 = 0; g2 < NSEG; ++g2)
            s += lds[g2 * (NB * OT + 1) + br * OT + orr];
        out[(size_t)(b0 + br) * OUT_DIM + blockIdx.x * OT + orr] =
            s * 0.6931471805599453f;   // * ln2
    }
}

extern "C" void kernel_launch(void* const* d_in, const int* in_sizes, int n_in,
                              void* d_out, int out_size, void* d_ws, size_t ws_size,
                              hipStream_t stream) {
    const float* x  = (const float*)d_in[0];
    // d_in[1] = slopes (arange(6)) — implicit in the polynomial powers.
    const float* wp = (const float*)d_in[2];
    const float* wq = (const float*)d_in[3];
    float* out = (float*)d_out;

    dim3 grid(OUT_DIM / OT, BATCH / NB);   // 32 x 16 = 512 blocks
    tropical_fused<<<grid, 256, 0, stream>>>(x, wp, wq, out);
}